// Round 4
// baseline (352.882 us; speedup 1.0000x reference)
//
#include <hip/hip_runtime.h>
#include <hip/hip_bf16.h>

#define TILE 128
#define KD 64
#define PAD 4

// out = i0e(z) * exp(z - 20), z = 20*sqrt((1+dot)/2), dot in [-1,1]
__device__ __forceinline__ float bessel_out(float dot) {
    dot = fminf(fmaxf(dot, -1.0f), 1.0f);
    float h = 0.5f + 0.5f * dot;                 // (1+dot)/2 in [0,1]
    float z = 20.0f * __builtin_amdgcn_sqrtf(h);

    // large-z (z > 3.75): i0e(z) = P(u)/sqrt(z), u = 3.75/z  (A&S 9.8.2)
    float u = 3.75f * __builtin_amdgcn_rcpf(z);
    float pl = 0.00392377f;
    pl = __builtin_fmaf(pl, u, -0.01647633f);
    pl = __builtin_fmaf(pl, u,  0.02635537f);
    pl = __builtin_fmaf(pl, u, -0.02057706f);
    pl = __builtin_fmaf(pl, u,  0.00916281f);
    pl = __builtin_fmaf(pl, u, -0.00157565f);
    pl = __builtin_fmaf(pl, u,  0.00225319f);
    pl = __builtin_fmaf(pl, u,  0.01328592f);
    pl = __builtin_fmaf(pl, u,  0.39894228f);
    float ebig = __builtin_amdgcn_exp2f((z - 20.0f) * 1.4426950408889634f);
    float big  = pl * __builtin_amdgcn_rsqf(z) * ebig;

    // small-z (z <= 3.75): out = I0(z)*e^-20, t = (z/3.75)^2 = h*400/14.0625 (A&S 9.8.1)
    float t = h * 28.444444444444443f;
    float ps = 0.0045813f;
    ps = __builtin_fmaf(ps, t, 0.0360768f);
    ps = __builtin_fmaf(ps, t, 0.2659732f);
    ps = __builtin_fmaf(ps, t, 1.2067492f);
    ps = __builtin_fmaf(ps, t, 3.0899424f);
    ps = __builtin_fmaf(ps, t, 3.5156229f);
    ps = __builtin_fmaf(ps, t, 1.0f);
    float small = ps * 2.0611536224385579e-9f;   // * e^-20

    return z > 3.75f ? big : small;
}

// out[n,m] = f( X_n . Y_m ), fp32 output (the reference's output dtype).
__global__ __launch_bounds__(256, 2)
void bessel_gemm(const float* __restrict__ X, const float* __restrict__ Y,
                 float* __restrict__ O, int M) {
    // LDS tiles stored transposed: [k][row] so compute-phase reads are
    // contiguous float4 across rows (broadcast/2-way, conflict-free).
    __shared__ float xs[KD][TILE + PAD];
    __shared__ float ys[KD][TILE + PAD];

    const int tid = threadIdx.x;
    const int bx  = blockIdx.x;   // output col tile (indexes Y)
    const int by  = blockIdx.y;   // output row tile (indexes X)

    // ---- stage tiles (d=64 entirely; no K loop) ----
    {
        const int r  = tid & 127;            // row within tile
        const int ks = (tid >> 7) << 5;      // k start: 0 or 32
        const float4* sx = reinterpret_cast<const float4*>(X + (size_t)(by * TILE + r) * KD + ks);
        const float4* sy = reinterpret_cast<const float4*>(Y + (size_t)(bx * TILE + r) * KD + ks);
        #pragma unroll
        for (int i = 0; i < 8; ++i) {
            float4 v = sx[i];
            int k = ks + i * 4;
            xs[k + 0][r] = v.x; xs[k + 1][r] = v.y; xs[k + 2][r] = v.z; xs[k + 3][r] = v.w;
        }
        #pragma unroll
        for (int i = 0; i < 8; ++i) {
            float4 v = sy[i];
            int k = ks + i * 4;
            ys[k + 0][r] = v.x; ys[k + 1][r] = v.y; ys[k + 2][r] = v.z; ys[k + 3][r] = v.w;
        }
    }
    __syncthreads();

    const int tx = tid & 15;    // 16 col-threads
    const int ty = tid >> 4;    // 16 row-threads

    float acc[8][8];
    #pragma unroll
    for (int i = 0; i < 8; ++i)
        #pragma unroll
        for (int j = 0; j < 8; ++j) acc[i][j] = 0.0f;

    // rows covered: hh*64 + ty*4 + i ; cols covered: g*64 + tx*4 + j
    #pragma unroll 2
    for (int k = 0; k < KD; ++k) {
        float4 a0 = *reinterpret_cast<const float4*>(&xs[k][ty * 4]);
        float4 a1 = *reinterpret_cast<const float4*>(&xs[k][ty * 4 + 64]);
        float4 b0 = *reinterpret_cast<const float4*>(&ys[k][tx * 4]);
        float4 b1 = *reinterpret_cast<const float4*>(&ys[k][tx * 4 + 64]);
        float a[8] = {a0.x, a0.y, a0.z, a0.w, a1.x, a1.y, a1.z, a1.w};
        float b[8] = {b0.x, b0.y, b0.z, b0.w, b1.x, b1.y, b1.z, b1.w};
        #pragma unroll
        for (int i = 0; i < 8; ++i)
            #pragma unroll
            for (int j = 0; j < 8; ++j)
                acc[i][j] = __builtin_fmaf(a[i], b[j], acc[i][j]);
    }

    // ---- epilogue: transcendental + coalesced float4 stores (fp32 out) ----
    #pragma unroll
    for (int hh = 0; hh < 2; ++hh) {
        #pragma unroll
        for (int i = 0; i < 4; ++i) {
            const int row = by * TILE + hh * 64 + ty * 4 + i;
            float* orow = O + (size_t)row * M + bx * TILE;
            #pragma unroll
            for (int g = 0; g < 2; ++g) {
                float4 p;
                p.x = bessel_out(acc[hh * 4 + i][g * 4 + 0]);
                p.y = bessel_out(acc[hh * 4 + i][g * 4 + 1]);
                p.z = bessel_out(acc[hh * 4 + i][g * 4 + 2]);
                p.w = bessel_out(acc[hh * 4 + i][g * 4 + 3]);
                *reinterpret_cast<float4*>(orow + g * 64 + tx * 4) = p;
            }
        }
    }
}

extern "C" void kernel_launch(void* const* d_in, const int* in_sizes, int n_in,
                              void* d_out, int out_size, void* d_ws, size_t ws_size,
                              hipStream_t stream) {
    const float* X = (const float*)d_in[0];
    const float* Y = (const float*)d_in[1];
    float* O = (float*)d_out;                 // fp32: the reference's output dtype
    const int N = in_sizes[0] / KD;   // 8192
    const int M = in_sizes[1] / KD;   // 8192
    dim3 grid(M / TILE, N / TILE);    // (64, 64)
    bessel_gemm<<<grid, dim3(256), 0, stream>>>(X, Y, O, M);
}